// Round 1
// 440.887 us; speedup vs baseline: 1.0446x; 1.0446x over previous
//
#include <hip/hip_runtime.h>

#define HW   262144      // 512*512
#define CCH  19
#define BB   8
#define NPIX 39845888ull // B*C*HW

typedef float f4 __attribute__((ext_vector_type(4)));

// ---------------- Kernel A: argmax over channels + 8x8 histogram -> patches^T ----------------
// grid: B*64 blocks (one per (b, bh) 8-row strip), 512 threads.
// Output pT layout: [bc][k][l] with row stride 20 floats (k=0..255, l=0..15, pad 4).
__global__ __launch_bounds__(512) void argmax_hist_kernel(
    const float* __restrict__ x, float* __restrict__ pT)
{
    int bid = blockIdx.x;          // b*64 + bh
    int b   = bid >> 6;
    int bh  = bid & 63;
    int t   = threadIdx.x;

    __shared__ int counts[CCH * 64];
    for (int i = t; i < CCH * 64; i += 512) counts[i] = 0;
    __syncthreads();

    // strip: rows [bh*8, bh*8+8) x 512 cols, contiguous 4096 floats per channel
    const float* xb = x + (size_t)b * CCH * HW + (size_t)bh * 4096;
    #pragma unroll
    for (int it = 0; it < 2; ++it) {
        int q = it * 512 + t;                       // float4-quad index in strip [0,1024)
        const float4* xq = (const float4*)xb + q;   // channel stride = HW/4 float4s
        float4 best = xq[0];
        int bx = 0, by = 0, bz = 0, bw4 = 0;
        #pragma unroll
        for (int c = 1; c < CCH; ++c) {
            float4 v = xq[c * (HW / 4)];
            if (v.x > best.x) { best.x = v.x; bx  = c; }
            if (v.y > best.y) { best.y = v.y; by  = c; }
            if (v.z > best.z) { best.z = v.z; bz  = c; }
            if (v.w > best.w) { best.w = v.w; bw4 = c; }
        }
        int off = q * 4;                 // pixel offset in strip; 4 pixels share one 8-block
        int blk = (off & 511) >> 3;      // bw in [0,64)
        atomicAdd(&counts[bx  * 64 + blk], 1);
        atomicAdd(&counts[by  * 64 + blk], 1);
        atomicAdd(&counts[bz  * 64 + blk], 1);
        atomicAdd(&counts[bw4 * 64 + blk], 1);
    }
    __syncthreads();

    // write patches^T: l = (bh/16)*4 + bw/16 ; k = (bh%16)*16 + bw%16
    int l_hi = (bh >> 4) * 4;
    int k_hi = (bh & 15) << 4;
    for (int u = t; u < CCH * 64; u += 512) {
        int c  = u >> 6;
        int bw = u & 63;
        int l  = l_hi + (bw >> 4);
        int k  = k_hi | (bw & 15);
        pT[((size_t)(b * CCH + c) * 256 + k) * 20 + l] =
            (float)counts[u] * (1.0f / 64.0f);
    }
}

// ---------------- Kernel C: per-tile bmm + fold + elementwise combine (fully vectorized) ----
// grid: B*C*32 blocks (one per (bc, mi) tile-row: 16 rows x 512 cols), 256 threads.
// Thread t owns two float4 column-groups per row: cols [4j,4j+3] (tile mj0) and
// [256+4j, 256+4j+3] (tile mj0+16). The 4 pixels of a group share one att row
// (same tile) but use 4 consecutive p-rows k = r*16 + cc0 + {0..3}.
__global__ __launch_bounds__(256) void apply_kernel(
    const float* __restrict__ x, const float* __restrict__ att,
    const float* __restrict__ pT, float* __restrict__ out)
{
    int t  = threadIdx.x;
    int bc = blockIdx.x >> 5;
    int mi = blockIdx.x & 31;

    __shared__ __align__(16) float p_lds[256 * 20];
    // vectorized staging: 1280 float4 (rows are 5 f4 each, layout identical to pT)
    {
        const f4* pb4 = (const f4*)(pT + (size_t)bc * 5120);
        f4* pl4 = (f4*)p_lds;
        #pragma unroll
        for (int i = 0; i < 5; ++i) pl4[t + i * 256] = pb4[t + i * 256];
    }

    int j   = t & 63;          // column group 0..63  (col0 = 4*j)
    int rq  = t >> 6;          // row-quadrant 0..3 (wave id)
    int mj0 = j >> 2;          // tile column 0..15
    int cc0 = (j & 3) << 2;    // within-tile col base: 0,4,8,12

    const float* ab = att + ((size_t)bc * 1024 + (size_t)mi * 32) * 16;
    const f4* a0p = (const f4*)(ab + mj0 * 16);
    const f4* a1p = (const f4*)(ab + (mj0 + 16) * 16);
    f4 a00 = a0p[0], a01 = a0p[1], a02 = a0p[2], a03 = a0p[3];
    f4 a10 = a1p[0], a11 = a1p[1], a12 = a1p[2], a13 = a1p[3];
    __syncthreads();

    size_t gb = (size_t)bc * HW + (size_t)mi * 8192;
    const f4* xg  = (const f4*)(x + gb);
    f4* o0g = (f4*)(out + gb);
    f4* o1g = (f4*)(out + NPIX + gb);

    #pragma unroll
    for (int it = 0; it < 4; ++it) {
        int r  = it * 4 + rq;          // row within tile 0..15 (uniform per wave)
        int kb = r * 16 + cc0;         // p-row base for this thread's 4 pixels
        f4 cA, cB;
        #pragma unroll
        for (int d = 0; d < 4; ++d) {
            const f4* pv = (const f4*)&p_lds[(kb + d) * 20];
            f4 p0 = pv[0], p1 = pv[1], p2 = pv[2], p3 = pv[3];
            f4 s0 = a00 * p0 + a01 * p1 + a02 * p2 + a03 * p3;
            f4 s1 = a10 * p0 + a11 * p1 + a12 * p2 + a13 * p3;
            cA[d] = s0[0] + s0[1] + s0[2] + s0[3];
            cB[d] = s1[0] + s1[1] + s1[2] + s1[3];
        }
        int rowo = r * 128 + j;        // f4 index: row r, first column half
        f4 v0 = xg[rowo];
        f4 v1 = xg[rowo + 64];         // +256 floats = second column half
        f4 y0 = v0 + cA * v0;
        f4 y1 = v1 + cB * v1;
        f4 z0 = y0 + cA * y0;
        f4 z1 = y1 + cB * y1;
        __builtin_nontemporal_store(z0, &o0g[rowo]);
        __builtin_nontemporal_store(z1, &o0g[rowo + 64]);
        __builtin_nontemporal_store(cA, &o1g[rowo]);
        __builtin_nontemporal_store(cB, &o1g[rowo + 64]);
    }
}

extern "C" void kernel_launch(void* const* d_in, const int* in_sizes, int n_in,
                              void* d_out, int out_size, void* d_ws, size_t ws_size,
                              hipStream_t stream) {
    const float* x   = (const float*)d_in[0];
    const float* att = (const float*)d_in[1];
    float* pT  = (float*)d_ws;      // 152 * 5120 floats = ~3.1 MB
    float* out = (float*)d_out;

    argmax_hist_kernel<<<BB * 64, 512, 0, stream>>>(x, pT);
    apply_kernel<<<BB * CCH * 32, 256, 0, stream>>>(x, att, pT, out);
}